// Round 2
// baseline (189.078 us; speedup 1.0000x reference)
//
#include <hip/hip_runtime.h>

// MaskLoss, 2-dispatch pipeline (no memset, no grid.sync, no global hist atomics):
//   kA (1024 blocks, 8/image): read hr+sr once. Per-block LDS histograms of
//       {count, sr-sum} binned by gray u16>>5; plain slab stores; per-block
//       min/max and sum(sr^2); border-pixel grays (1024 u16/image) to ws.
//   kB (128 blocks, 1/image): sum 8 slabs; suffix scans of N, S_gray
//       (bin-midpoint model -> Lloyd t bit-identical to validated baseline),
//       and S_sv; 20 Lloyd iters; closed-form dual MSE from suffix sums
//       (fractional boundary bin); EXACT border vote from stored border grays;
//       atomic accumulate + ticket; last block writes out.

constexpr int NB   = 2048;       // histogram bins (u16 >> 5)
constexpr int NPIX = 65536;      // 256*256
constexpr int KM_ITERS = 20;
constexpr float QINV = 1.0f / 65536.0f;   // u16 -> gray
constexpr float BINW = 1.0f / 2048.0f;    // bin width in gray units

// ws byte offsets (nothing pre-zeroed: every word written before read;
// acc/done ticket is initialized by kA block 0 each launch)
constexpr size_t OFF_MMN = 0;                    // 1024 u32 per-block min
constexpr size_t OFF_MMX = 4096;                 // 1024 u32 per-block max
constexpr size_t OFF_SR2 = 8192;                 // 1024 f32 per-block sum(sr^2)
constexpr size_t OFF_ACC = 12288;                // f32 acc @+0, u32 done @+4
constexpr size_t OFF_BG  = 16384;                // 128*1024 u16 border grays (256 KB)
constexpr size_t OFF_CNT = OFF_BG + 262144;      // 1024*2048 u32 count slabs (8 MB)
constexpr size_t OFF_SV  = OFF_CNT + 8388608;    // 1024*2048 f32 svsum slabs (8 MB)

__device__ __forceinline__ float waveSumF(float v) {
#pragma unroll
    for (int off = 32; off > 0; off >>= 1) v += __shfl_down(v, off, 64);
    return v;
}
__device__ __forceinline__ unsigned waveMinU(unsigned v) {
#pragma unroll
    for (int off = 32; off > 0; off >>= 1) v = min(v, (unsigned)__shfl_down((int)v, off, 64));
    return v;
}
__device__ __forceinline__ unsigned waveMaxU(unsigned v) {
#pragma unroll
    for (int off = 32; off > 0; off >>= 1) v = max(v, (unsigned)__shfl_down((int)v, off, 64));
    return v;
}

// ---------------- [A] gray -> {count,svsum} hist + min/max + sr^2 + borders --
__global__ __launch_bounds__(256) void kA_hist(
        const float* __restrict__ hr, const float* __restrict__ sr,
        unsigned* __restrict__ mmn, unsigned* __restrict__ mmx,
        float* __restrict__ bsr2, ushort* __restrict__ bg,
        unsigned* __restrict__ cslab, float* __restrict__ vslab,
        float* __restrict__ acc, unsigned* __restrict__ done) {
    const int blk = blockIdx.x, img = blk >> 3, part = blk & 7;
    const int tid = threadIdx.x, lane = tid & 63, wid = tid >> 6;

    __shared__ unsigned hc[NB];
    __shared__ float    hv[NB];
    __shared__ unsigned smn[4], smx[4];
    __shared__ float    ssq[4];
    for (int j = tid; j < NB; j += 256) { hc[j] = 0u; hv[j] = 0.0f; }
    if (blk == 0 && tid == 0) { *acc = 0.0f; *done = 0u; }   // ticket init (pre-kB)
    __syncthreads();

    const float* rr = hr + (size_t)img * 3 * NPIX;
    const float* gg = rr + NPIX;
    const float* bb = gg + NPIX;
    const float* sp = sr + (size_t)img * NPIX;
    ushort* bgp = bg + (size_t)img * 1024;

    unsigned umn = 65535u, umx = 0u;
    float sq = 0.0f;
#pragma unroll
    for (int i = 0; i < 8; ++i) {
        const int p = part * 8192 + i * 1024 + tid * 4;
        float4 r4 = *(const float4*)(rr + p);
        float4 g4 = *(const float4*)(gg + p);
        float4 b4 = *(const float4*)(bb + p);
        float4 s4 = *(const float4*)(sp + p);
        const float x[4] = { (r4.x + g4.x + b4.x) * (1.0f / 3.0f),
                             (r4.y + g4.y + b4.y) * (1.0f / 3.0f),
                             (r4.z + g4.z + b4.z) * (1.0f / 3.0f),
                             (r4.w + g4.w + b4.w) * (1.0f / 3.0f) };
        const float sv[4] = { s4.x, s4.y, s4.z, s4.w };
        unsigned u[4];
#pragma unroll
        for (int j = 0; j < 4; ++j) {
            unsigned uu = (unsigned)(x[j] * 65536.0f);
            uu = min(uu, 65535u);
            u[j] = uu;
            umn = min(umn, uu); umx = max(umx, uu);
            atomicAdd(&hc[uu >> 5], 1u);
            atomicAdd(&hv[uu >> 5], sv[j]);
            sq += sv[j] * sv[j];
        }
        const int row = p >> 8, colb = p & 255;   // 4 px share a row
        if (row == 0) {
            ushort4 q; q.x = (ushort)u[0]; q.y = (ushort)u[1];
            q.z = (ushort)u[2]; q.w = (ushort)u[3];
            *(ushort4*)(bgp + colb) = q;
        }
        if (row == 255) {
            ushort4 q; q.x = (ushort)u[0]; q.y = (ushort)u[1];
            q.z = (ushort)u[2]; q.w = (ushort)u[3];
            *(ushort4*)(bgp + 256 + colb) = q;
        }
        if (colb == 0)   bgp[512 + row] = (ushort)u[0];
        if (colb == 252) bgp[768 + row] = (ushort)u[3];
    }
    __syncthreads();

    // plain coalesced slab stores (no global atomics)
    for (int j = tid; j < NB; j += 256) {
        cslab[(size_t)blk * NB + j] = hc[j];
        vslab[(size_t)blk * NB + j] = hv[j];
    }

    sq = waveSumF(sq); umn = waveMinU(umn); umx = waveMaxU(umx);
    if (lane == 0) { ssq[wid] = sq; smn[wid] = umn; smx[wid] = umx; }
    __syncthreads();
    if (tid == 0) {
        bsr2[blk] = ssq[0] + ssq[1] + ssq[2] + ssq[3];
        mmn[blk] = min(min(smn[0], smn[1]), min(smn[2], smn[3]));
        mmx[blk] = max(max(smx[0], smx[1]), max(smx[2], smx[3]));
    }
}

// ---------------- [B] per-image: scan + Lloyd + MSE + exact vote + reduce ----
__global__ __launch_bounds__(256) void kB_all(
        const unsigned* __restrict__ mmn, const unsigned* __restrict__ mmx,
        const float* __restrict__ bsr2, const ushort* __restrict__ bg,
        const unsigned* __restrict__ cslab, const float* __restrict__ vslab,
        float* __restrict__ acc, unsigned* __restrict__ done,
        float* __restrict__ out) {
    const int img = blockIdx.x, tid = threadIdx.x;
    const int lane = tid & 63, wid = tid >> 6;
    __shared__ float sN[NB + 1], sS[NB + 1], sV[NB + 1];
    __shared__ float tN[256], tS[256], tV[256];
    __shared__ float bres[4];           // {t, hi, mse0, mse1}
    __shared__ float4 sB4[4];

    // ---- sum the 8 slabs ----
    const int base = tid * 8;
    unsigned aC[8] = {0u,0u,0u,0u,0u,0u,0u,0u};
    float    aV[8] = {0.f,0.f,0.f,0.f,0.f,0.f,0.f,0.f};
#pragma unroll
    for (int s = 0; s < 8; ++s) {
        const unsigned* cp = cslab + (size_t)(img * 8 + s) * NB + base;
        const float*    vp = vslab + (size_t)(img * 8 + s) * NB + base;
        const uint4  c0 = *(const uint4*)cp;
        const uint4  c1 = *(const uint4*)(cp + 4);
        const float4 v0 = *(const float4*)vp;
        const float4 v1 = *(const float4*)(vp + 4);
        aC[0] += c0.x; aC[1] += c0.y; aC[2] += c0.z; aC[3] += c0.w;
        aC[4] += c1.x; aC[5] += c1.y; aC[6] += c1.z; aC[7] += c1.w;
        aV[0] += v0.x; aV[1] += v0.y; aV[2] += v0.z; aV[3] += v0.w;
        aV[4] += v1.x; aV[5] += v1.y; aV[6] += v1.z; aV[7] += v1.w;
    }

    // ---- triple suffix scan (N / S_gray midpoint-model / S_sv) ----
    float n8[8], s8[8], v8[8];
#pragma unroll
    for (int u = 0; u < 8; ++u) {
        const float c = (float)aC[u];
        n8[u] = c;
        s8[u] = c * (((float)(base + u) + 0.484375f) * BINW);  // mean u in bin = 32k+15.5
        v8[u] = aV[u];
    }
    float accN = 0.0f, accS = 0.0f, accV = 0.0f;
#pragma unroll
    for (int u = 7; u >= 0; --u) {
        accN += n8[u]; n8[u] = accN;
        accS += s8[u]; s8[u] = accS;
        accV += v8[u]; v8[u] = accV;
    }
    tN[tid] = accN; tS[tid] = accS; tV[tid] = accV;
    __syncthreads();
    for (int off = 1; off < 256; off <<= 1) {
        float aNN = 0.0f, aSS = 0.0f, aVV = 0.0f;
        if (tid + off < 256) { aNN = tN[tid + off]; aSS = tS[tid + off]; aVV = tV[tid + off]; }
        __syncthreads();
        tN[tid] += aNN; tS[tid] += aSS; tV[tid] += aVV;
        __syncthreads();
    }
    const float exN = (tid < 255) ? tN[tid + 1] : 0.0f;
    const float exS = (tid < 255) ? tS[tid + 1] : 0.0f;
    const float exV = (tid < 255) ? tV[tid + 1] : 0.0f;
#pragma unroll
    for (int u = 0; u < 8; ++u) {
        sN[base + u] = n8[u] + exN;
        sS[base + u] = s8[u] + exS;
        sV[base + u] = v8[u] + exV;
    }
    if (tid == 0) { sN[NB] = 0.0f; sS[NB] = 0.0f; sV[NB] = 0.0f; }
    __syncthreads();

    // ---- Lloyd (arithmetic verbatim from validated baseline) + dual MSE ----
    if (tid == 0) {
        unsigned bmn = 65535u, bmx = 0u;
#pragma unroll
        for (int s = 0; s < 8; ++s) {
            bmn = min(bmn, mmn[img * 8 + s]);
            bmx = max(bmx, mmx[img * 8 + s]);
        }
        float c0 = (float)bmn * QINV;
        float c1 = (float)bmx * QINV;
        const float Stot = sS[0];
        const float Ntot = (float)NPIX;
#pragma unroll 1
        for (int it = 0; it < KM_ITERS; ++it) {
            const float t = 0.5f * (c0 + c1);
            float n1, s1;
            if (c1 == c0) { n1 = 0.0f; s1 = 0.0f; }
            else {
                const float f = t * (float)NB;
                int k = (int)floorf(f);
                k = max(0, min(NB - 1, k));
                float frac = (float)(k + 1) - f;             // fraction of bin k above t
                frac = fminf(fmaxf(frac, 0.0f), 1.0f);
                const float cntk = sN[k] - sN[k + 1];
                const float aNt = sN[k + 1] + cntk * frac;   // count of x > t
                const float aSt = sS[k + 1] +
                                  cntk * frac * 0.5f * (t + (float)(k + 1) * BINW);
                if (c1 > c0) { n1 = aNt; s1 = aSt; }
                else         { n1 = Ntot - aNt; s1 = Stot - aSt; }
            }
            const float c1n = s1 / fmaxf(n1, 1.0f);
            const float c0n = (Stot - s1) / fmaxf(Ntot - n1, 1.0f);
            if (c1n == c1 && c0n == c0) break;   // exact fixed point
            c0 = c0n; c1 = c1n;
        }

        float Sr2 = 0.0f;
#pragma unroll
        for (int s = 0; s < 8; ++s) Sr2 += bsr2[img * 8 + s];
        const float SvTot = sV[0];

        float tf, hii, n1, s1v;
        if (c1 == c0) { tf = -1e30f; hii = 0.0f; n1 = 0.0f; s1v = 0.0f; }
        else {
            tf = 0.5f * (c0 + c1);
            const float f = tf * (float)NB;
            int k = (int)floorf(f);
            k = max(0, min(NB - 1, k));
            float frac = (float)(k + 1) - f;
            frac = fminf(fmaxf(frac, 0.0f), 1.0f);
            const float cntk = sN[k] - sN[k + 1];
            const float aNt = sN[k + 1] + cntk * frac;       // count of x > t
            const float svk = sV[k] - sV[k + 1];
            const float aSv = sV[k + 1] + svk * frac;        // sr-mass above t
            if (c1 > c0) { hii = 1.0f; n1 = aNt;        s1v = aSv; }
            else         { hii = 0.0f; n1 = Ntot - aNt; s1v = SvTot - aSv; }
        }
        bres[0] = tf; bres[1] = hii;
        bres[2] = Sr2 - 2.0f * s1v + n1;                       // mse, mask as-is
        bres[3] = Sr2 - 2.0f * (SvTot - s1v) + (Ntot - n1);    // mse, mask flipped
    }
    __syncthreads();

    // ---- EXACT border counts + vote + global accumulate ----
    const float tf = bres[0];
    const bool hi = (bres[1] != 0.0f);
    const ushort* bp = bg + (size_t)img * 1024;
    const float x0 = (float)bp[tid]       * QINV;   // row 0, col tid
    const float x1 = (float)bp[256 + tid] * QINV;   // row 255
    const float x2 = (float)bp[512 + tid] * QINV;   // col 0, row tid
    const float x3 = (float)bp[768 + tid] * QINV;   // col 255
    float fr = (hi ? (x0 > tf) : (x0 < tf)) ? 1.0f : 0.0f;
    float lr = (hi ? (x1 > tf) : (x1 < tf)) ? 1.0f : 0.0f;
    float fc = (hi ? (x2 > tf) : (x2 < tf)) ? 1.0f : 0.0f;
    float lc = (hi ? (x3 > tf) : (x3 < tf)) ? 1.0f : 0.0f;
    fr = waveSumF(fr); lr = waveSumF(lr); fc = waveSumF(fc); lc = waveSumF(lc);
    if (lane == 0) sB4[wid] = make_float4(fr, lr, fc, lc);
    __syncthreads();
    if (tid == 0) {
        const float FR = sB4[0].x + sB4[1].x + sB4[2].x + sB4[3].x;
        const float LR = sB4[0].y + sB4[1].y + sB4[2].y + sB4[3].y;
        const float FC = sB4[0].z + sB4[1].z + sB4[2].z + sB4[3].z;
        const float LC = sB4[0].w + sB4[1].w + sB4[2].w + sB4[3].w;
        const int num = (FR > 128.0f) + (LR > 128.0f) + (FC > 128.0f) + (LC > 128.0f);
        const float chosen = (num >= 3) ? bres[3] : bres[2];
        atomicAdd(acc, chosen);
        __threadfence();
        const unsigned old = atomicAdd(done, 1u);
        if (old == 127u) {
            const float tot = atomicAdd(acc, 0.0f);   // all adds happened-before
            out[0] = tot * (1.0f / 8388608.0f);
        }
    }
}

extern "C" void kernel_launch(void* const* d_in, const int* in_sizes, int n_in,
                              void* d_out, int out_size, void* d_ws, size_t ws_size,
                              hipStream_t stream) {
    const float* hr = (const float*)d_in[0];   // [128,3,256,256] f32
    const float* sr = (const float*)d_in[1];   // [128,1,256,256] f32
    float* out = (float*)d_out;

    char* ws = (char*)d_ws;
    unsigned* mmn   = (unsigned*)(ws + OFF_MMN);
    unsigned* mmx   = (unsigned*)(ws + OFF_MMX);
    float*    bsr2  = (float*)(ws + OFF_SR2);
    float*    acc   = (float*)(ws + OFF_ACC);
    unsigned* done  = (unsigned*)(ws + OFF_ACC + 4);
    ushort*   bg    = (ushort*)(ws + OFF_BG);
    unsigned* cslab = (unsigned*)(ws + OFF_CNT);
    float*    vslab = (float*)(ws + OFF_SV);

    kA_hist<<<1024, 256, 0, stream>>>(hr, sr, mmn, mmx, bsr2, bg, cslab, vslab, acc, done);
    kB_all <<< 128, 256, 0, stream>>>(mmn, mmx, bsr2, bg, cslab, vslab, acc, done, out);
}

// Round 3
// 186.448 us; speedup vs baseline: 1.0141x; 1.0141x over previous
//
#include <hip/hip_runtime.h>

// MaskLoss, 2-dispatch + 2MB memset pipeline:
//   kA (1024 blocks x 512 threads, 8/image, 16 px/thread): read hr+sr once.
//       Single packed u64 LDS histogram atomic per pixel:
//         {count in bits [40..63], sum(sr) as 2^-24 fixed point in bits [0..39]}
//       Flush via global u64 atomics into per-image histogram (memset-zeroed).
//       Per-block min/max gray, sum(sr^2), border-pixel grays.
//   kB (128 blocks, 1/image): unpack per-image hist; triple suffix scan
//       (N / S_gray midpoint model -> Lloyd t BIT-IDENTICAL to validated
//       baseline / S_sr); 20 Lloyd iters; closed-form dual MSE; EXACT border
//       vote from stored border grays; atomic accumulate + ticket -> out.

constexpr int NB   = 2048;       // histogram bins (u16 >> 5)
constexpr int NPIX = 65536;      // 256*256
constexpr int KM_ITERS = 20;
constexpr float QINV = 1.0f / 65536.0f;    // u16 -> gray
constexpr float BINW = 1.0f / 2048.0f;     // bin width in gray units
constexpr unsigned long long CNT1   = 1ull << 40;   // one count in packed u64
constexpr unsigned long long SVMASK = CNT1 - 1;     // 40-bit sr-sum field

// ws byte offsets
constexpr size_t OFF_HIST = 0;                   // 128*2048 u64 = 2 MB (memset 0)
constexpr size_t OFF_MMN  = 2097152;             // 1024 u32 per-block min
constexpr size_t OFF_MMX  = OFF_MMN + 4096;      // 1024 u32 per-block max
constexpr size_t OFF_SR2  = OFF_MMX + 4096;      // 1024 f32 per-block sum(sr^2)
constexpr size_t OFF_ACC  = OFF_SR2 + 4096;      // f32 acc @+0, u32 done @+4
constexpr size_t OFF_BG   = OFF_ACC + 4096;      // 128*1024 u16 border grays (256 KB)
constexpr size_t MEMSET_BYTES = 2097152;         // hist only

__device__ __forceinline__ float waveSumF(float v) {
#pragma unroll
    for (int off = 32; off > 0; off >>= 1) v += __shfl_down(v, off, 64);
    return v;
}
__device__ __forceinline__ unsigned waveMinU(unsigned v) {
#pragma unroll
    for (int off = 32; off > 0; off >>= 1) v = min(v, (unsigned)__shfl_down((int)v, off, 64));
    return v;
}
__device__ __forceinline__ unsigned waveMaxU(unsigned v) {
#pragma unroll
    for (int off = 32; off > 0; off >>= 1) v = max(v, (unsigned)__shfl_down((int)v, off, 64));
    return v;
}

// ---- [A] packed u64 hist + min/max + sr^2 + border grays --------------------
__global__ __launch_bounds__(512) void kA_hist(
        const float* __restrict__ hr, const float* __restrict__ sr,
        unsigned long long* __restrict__ hist,
        unsigned* __restrict__ mmn, unsigned* __restrict__ mmx,
        float* __restrict__ bsr2, ushort* __restrict__ bg,
        float* __restrict__ acc, unsigned* __restrict__ done) {
    const int blk = blockIdx.x, img = blk >> 3, part = blk & 7;
    const int tid = threadIdx.x, lane = tid & 63, wid = tid >> 6;

    __shared__ unsigned long long h64[NB];      // 16 KB
    __shared__ unsigned smn[8], smx[8];
    __shared__ float    ssq[8];
    for (int j = tid; j < NB; j += 512) h64[j] = 0ull;
    if (blk == 0 && tid == 0) { *acc = 0.0f; *done = 0u; }   // ticket init (pre-kB)
    __syncthreads();

    const float* rr = hr + (size_t)img * 3 * NPIX;
    const float* gg = rr + NPIX;
    const float* bb = gg + NPIX;
    const float* sp = sr + (size_t)img * NPIX;
    ushort* bgp = bg + (size_t)img * 1024;

    unsigned umn = 65535u, umx = 0u;
    float sq = 0.0f;
#pragma unroll
    for (int i = 0; i < 4; ++i) {
        const int p = part * 8192 + i * 2048 + tid * 4;
        float4 r4 = *(const float4*)(rr + p);
        float4 g4 = *(const float4*)(gg + p);
        float4 b4 = *(const float4*)(bb + p);
        float4 s4 = *(const float4*)(sp + p);
        const float x[4] = { (r4.x + g4.x + b4.x) * (1.0f / 3.0f),
                             (r4.y + g4.y + b4.y) * (1.0f / 3.0f),
                             (r4.z + g4.z + b4.z) * (1.0f / 3.0f),
                             (r4.w + g4.w + b4.w) * (1.0f / 3.0f) };
        const float sv[4] = { s4.x, s4.y, s4.z, s4.w };
        unsigned u[4];
#pragma unroll
        for (int j = 0; j < 4; ++j) {
            unsigned uu = (unsigned)(x[j] * 65536.0f);
            uu = min(uu, 65535u);
            u[j] = uu;
            umn = min(umn, uu); umx = max(umx, uu);
            unsigned q = (unsigned)(sv[j] * 16777216.0f);    // exact: 2^24 scale
            q = min(q, 16777215u);
            atomicAdd(&h64[uu >> 5], CNT1 + (unsigned long long)q);
            sq += sv[j] * sv[j];
        }
        const int row = p >> 8, colb = p & 255;   // 4 px share a row
        if (row == 0) {
            ushort4 qq; qq.x = (ushort)u[0]; qq.y = (ushort)u[1];
            qq.z = (ushort)u[2]; qq.w = (ushort)u[3];
            *(ushort4*)(bgp + colb) = qq;
        }
        if (row == 255) {
            ushort4 qq; qq.x = (ushort)u[0]; qq.y = (ushort)u[1];
            qq.z = (ushort)u[2]; qq.w = (ushort)u[3];
            *(ushort4*)(bgp + 256 + colb) = qq;
        }
        if (colb == 0)   bgp[512 + row] = (ushort)u[0];
        if (colb == 252) bgp[768 + row] = (ushort)u[3];
    }
    __syncthreads();

    // flush LDS hist -> per-image global hist (u64 atomics, skip empty bins)
    unsigned long long* gh = hist + (size_t)img * NB;
    for (int j = tid; j < NB; j += 512) {
        const unsigned long long v = h64[j];
        if (v) atomicAdd(&gh[j], v);
    }

    sq = waveSumF(sq); umn = waveMinU(umn); umx = waveMaxU(umx);
    if (lane == 0) { ssq[wid] = sq; smn[wid] = umn; smx[wid] = umx; }
    __syncthreads();
    if (tid == 0) {
        float SQ = 0.0f; unsigned MN = 65535u, MX = 0u;
#pragma unroll
        for (int w = 0; w < 8; ++w) {
            SQ += ssq[w]; MN = min(MN, smn[w]); MX = max(MX, smx[w]);
        }
        bsr2[blk] = SQ; mmn[blk] = MN; mmx[blk] = MX;
    }
}

// ---- [B] per-image: unpack + scan + Lloyd + MSE + exact vote + reduce -------
__global__ __launch_bounds__(256) void kB_all(
        const unsigned* __restrict__ mmn, const unsigned* __restrict__ mmx,
        const float* __restrict__ bsr2, const ushort* __restrict__ bg,
        const unsigned long long* __restrict__ hist,
        float* __restrict__ acc, unsigned* __restrict__ done,
        float* __restrict__ out) {
    const int img = blockIdx.x, tid = threadIdx.x;
    const int lane = tid & 63, wid = tid >> 6;
    __shared__ float sN[NB + 1], sS[NB + 1], sV[NB + 1];
    __shared__ float tN[256], tS[256], tV[256];
    __shared__ float bres[4];           // {t, hi, mse0, mse1}
    __shared__ float4 sB4[4];

    // ---- unpack 8 bins/thread ----
    const int base = tid * 8;
    const unsigned long long* gh = hist + (size_t)img * NB + base;
    float n8[8], s8[8], v8[8];
#pragma unroll
    for (int u2 = 0; u2 < 4; ++u2) {
        const ulonglong2 vv = *(const ulonglong2*)(gh + u2 * 2);
        const unsigned long long va = vv.x, vb = vv.y;
        const float ca = (float)(unsigned)(va >> 40);
        const float cb = (float)(unsigned)(vb >> 40);
        n8[u2 * 2]     = ca;
        n8[u2 * 2 + 1] = cb;
        s8[u2 * 2]     = ca * (((float)(base + u2 * 2)     + 0.484375f) * BINW);
        s8[u2 * 2 + 1] = cb * (((float)(base + u2 * 2 + 1) + 0.484375f) * BINW);
        v8[u2 * 2]     = (float)(va & SVMASK) * (1.0f / 16777216.0f);
        v8[u2 * 2 + 1] = (float)(vb & SVMASK) * (1.0f / 16777216.0f);
    }

    // ---- triple suffix scan (N / S_gray midpoint-model / S_sr) ----
    float accN = 0.0f, accS = 0.0f, accV = 0.0f;
#pragma unroll
    for (int u = 7; u >= 0; --u) {
        accN += n8[u]; n8[u] = accN;
        accS += s8[u]; s8[u] = accS;
        accV += v8[u]; v8[u] = accV;
    }
    tN[tid] = accN; tS[tid] = accS; tV[tid] = accV;
    __syncthreads();
    for (int off = 1; off < 256; off <<= 1) {
        float aNN = 0.0f, aSS = 0.0f, aVV = 0.0f;
        if (tid + off < 256) { aNN = tN[tid + off]; aSS = tS[tid + off]; aVV = tV[tid + off]; }
        __syncthreads();
        tN[tid] += aNN; tS[tid] += aSS; tV[tid] += aVV;
        __syncthreads();
    }
    const float exN = (tid < 255) ? tN[tid + 1] : 0.0f;
    const float exS = (tid < 255) ? tS[tid + 1] : 0.0f;
    const float exV = (tid < 255) ? tV[tid + 1] : 0.0f;
#pragma unroll
    for (int u = 0; u < 8; ++u) {
        sN[base + u] = n8[u] + exN;
        sS[base + u] = s8[u] + exS;
        sV[base + u] = v8[u] + exV;
    }
    if (tid == 0) { sN[NB] = 0.0f; sS[NB] = 0.0f; sV[NB] = 0.0f; }
    __syncthreads();

    // ---- Lloyd (arithmetic verbatim from validated baseline) + dual MSE ----
    if (tid == 0) {
        unsigned bmn = 65535u, bmx = 0u;
#pragma unroll
        for (int s = 0; s < 8; ++s) {
            bmn = min(bmn, mmn[img * 8 + s]);
            bmx = max(bmx, mmx[img * 8 + s]);
        }
        float c0 = (float)bmn * QINV;
        float c1 = (float)bmx * QINV;
        const float Stot = sS[0];
        const float Ntot = (float)NPIX;
#pragma unroll 1
        for (int it = 0; it < KM_ITERS; ++it) {
            const float t = 0.5f * (c0 + c1);
            float n1, s1;
            if (c1 == c0) { n1 = 0.0f; s1 = 0.0f; }
            else {
                const float f = t * (float)NB;
                int k = (int)floorf(f);
                k = max(0, min(NB - 1, k));
                float frac = (float)(k + 1) - f;             // fraction of bin k above t
                frac = fminf(fmaxf(frac, 0.0f), 1.0f);
                const float cntk = sN[k] - sN[k + 1];
                const float aNt = sN[k + 1] + cntk * frac;   // count of x > t
                const float aSt = sS[k + 1] +
                                  cntk * frac * 0.5f * (t + (float)(k + 1) * BINW);
                if (c1 > c0) { n1 = aNt; s1 = aSt; }
                else         { n1 = Ntot - aNt; s1 = Stot - aSt; }
            }
            const float c1n = s1 / fmaxf(n1, 1.0f);
            const float c0n = (Stot - s1) / fmaxf(Ntot - n1, 1.0f);
            if (c1n == c1 && c0n == c0) break;   // exact fixed point
            c0 = c0n; c1 = c1n;
        }

        float Sr2 = 0.0f;
#pragma unroll
        for (int s = 0; s < 8; ++s) Sr2 += bsr2[img * 8 + s];
        const float SvTot = sV[0];

        float tf, hii, n1, s1v;
        if (c1 == c0) { tf = -1e30f; hii = 0.0f; n1 = 0.0f; s1v = 0.0f; }
        else {
            tf = 0.5f * (c0 + c1);
            const float f = tf * (float)NB;
            int k = (int)floorf(f);
            k = max(0, min(NB - 1, k));
            float frac = (float)(k + 1) - f;
            frac = fminf(fmaxf(frac, 0.0f), 1.0f);
            const float cntk = sN[k] - sN[k + 1];
            const float aNt = sN[k + 1] + cntk * frac;       // count of x > t
            const float svk = sV[k] - sV[k + 1];
            const float aSv = sV[k + 1] + svk * frac;        // sr-mass above t
            if (c1 > c0) { hii = 1.0f; n1 = aNt;        s1v = aSv; }
            else         { hii = 0.0f; n1 = Ntot - aNt; s1v = SvTot - aSv; }
        }
        bres[0] = tf; bres[1] = hii;
        bres[2] = Sr2 - 2.0f * s1v + n1;                       // mse, mask as-is
        bres[3] = Sr2 - 2.0f * (SvTot - s1v) + (Ntot - n1);    // mse, mask flipped
    }
    __syncthreads();

    // ---- EXACT border counts + vote + global accumulate ----
    const float tf = bres[0];
    const bool hi = (bres[1] != 0.0f);
    const ushort* bp = bg + (size_t)img * 1024;
    const float x0 = (float)bp[tid]       * QINV;   // row 0, col tid
    const float x1 = (float)bp[256 + tid] * QINV;   // row 255
    const float x2 = (float)bp[512 + tid] * QINV;   // col 0, row tid
    const float x3 = (float)bp[768 + tid] * QINV;   // col 255
    float fr = (hi ? (x0 > tf) : (x0 < tf)) ? 1.0f : 0.0f;
    float lr = (hi ? (x1 > tf) : (x1 < tf)) ? 1.0f : 0.0f;
    float fc = (hi ? (x2 > tf) : (x2 < tf)) ? 1.0f : 0.0f;
    float lc = (hi ? (x3 > tf) : (x3 < tf)) ? 1.0f : 0.0f;
    fr = waveSumF(fr); lr = waveSumF(lr); fc = waveSumF(fc); lc = waveSumF(lc);
    if (lane == 0) sB4[wid] = make_float4(fr, lr, fc, lc);
    __syncthreads();
    if (tid == 0) {
        const float FR = sB4[0].x + sB4[1].x + sB4[2].x + sB4[3].x;
        const float LR = sB4[0].y + sB4[1].y + sB4[2].y + sB4[3].y;
        const float FC = sB4[0].z + sB4[1].z + sB4[2].z + sB4[3].z;
        const float LC = sB4[0].w + sB4[1].w + sB4[2].w + sB4[3].w;
        const int num = (FR > 128.0f) + (LR > 128.0f) + (FC > 128.0f) + (LC > 128.0f);
        const float chosen = (num >= 3) ? bres[3] : bres[2];
        atomicAdd(acc, chosen);
        __threadfence();
        const unsigned old = atomicAdd(done, 1u);
        if (old == 127u) {
            const float tot = atomicAdd(acc, 0.0f);   // all adds happened-before
            out[0] = tot * (1.0f / 8388608.0f);
        }
    }
}

extern "C" void kernel_launch(void* const* d_in, const int* in_sizes, int n_in,
                              void* d_out, int out_size, void* d_ws, size_t ws_size,
                              hipStream_t stream) {
    const float* hr = (const float*)d_in[0];   // [128,3,256,256] f32
    const float* sr = (const float*)d_in[1];   // [128,1,256,256] f32
    float* out = (float*)d_out;

    char* ws = (char*)d_ws;
    unsigned long long* hist = (unsigned long long*)(ws + OFF_HIST);
    unsigned* mmn  = (unsigned*)(ws + OFF_MMN);
    unsigned* mmx  = (unsigned*)(ws + OFF_MMX);
    float*    bsr2 = (float*)(ws + OFF_SR2);
    float*    acc  = (float*)(ws + OFF_ACC);
    unsigned* done = (unsigned*)(ws + OFF_ACC + 4);
    ushort*   bg   = (ushort*)(ws + OFF_BG);

    hipMemsetAsync(hist, 0, MEMSET_BYTES, stream);
    kA_hist<<<1024, 512, 0, stream>>>(hr, sr, hist, mmn, mmx, bsr2, bg, acc, done);
    kB_all <<< 128, 256, 0, stream>>>(mmn, mmx, bsr2, bg, hist, acc, done, out);
}